// Round 9
// baseline (274.890 us; speedup 1.0000x reference)
//
#include <hip/hip_runtime.h>
#include <hip/hip_bf16.h>

typedef unsigned short u16;
typedef unsigned char u8;
typedef __bf16 bf16x8 __attribute__((ext_vector_type(8)));
typedef float f32x4 __attribute__((ext_vector_type(4)));

#define N_ROWS 8192
#define M_ROWS 4096
#define E_DIM  512
#define KSPLIT 4
#define INV_T  0.04419417382415922f   // 1/22.627416997969522

// ---------- helpers ----------
__device__ __forceinline__ u16 f2bf(float f) {
    unsigned u = __float_as_uint(f);
    u += 0x7FFF + ((u >> 16) & 1);   // RNE
    return (u16)(u >> 16);
}
__device__ __forceinline__ float bf2f(u16 u) {
    return __uint_as_float(((unsigned)u) << 16);
}
__device__ __forceinline__ u8 f2fp8(float f) {
    int p = __builtin_amdgcn_cvt_pk_fp8_f32(f, f, 0, false);
    return (u8)(p & 0xFF);
}
__device__ __forceinline__ unsigned pk4fp8(float f0, float f1, float f2, float f3) {
    int p01 = __builtin_amdgcn_cvt_pk_fp8_f32(f0, f1, 0, false);
    int p23 = __builtin_amdgcn_cvt_pk_fp8_f32(f2, f3, 0, false);
    return (unsigned)(p01 & 0xFFFF) | ((unsigned)p23 << 16);
}

#define GLD16(gp, lp) \
    __builtin_amdgcn_global_load_lds((const __attribute__((address_space(1))) void*)(gp), \
                                     (__attribute__((address_space(3))) void*)(lp), 16, 0, 0)

// ---------- cast fp32 -> bf16 ----------
__global__ __launch_bounds__(256)
void cast_bf(const float* __restrict__ in, u16* __restrict__ out, int n4) {
    int i = blockIdx.x * 256 + threadIdx.x;
    if (i < n4) {
        float4 f = reinterpret_cast<const float4*>(in)[i];
        ushort4 o;
        o.x = f2bf(f.x); o.y = f2bf(f.y); o.z = f2bf(f.z); o.w = f2bf(f.w);
        reinterpret_cast<ushort4*>(out)[i] = o;
    }
}

// ---------- cast fp32 -> bf16 + fp8 (obs) ----------
__global__ __launch_bounds__(256)
void cast_obs(const float* __restrict__ in, u16* __restrict__ out_bf,
              u8* __restrict__ out8, int n4) {
    int i = blockIdx.x * 256 + threadIdx.x;
    if (i < n4) {
        float4 f = reinterpret_cast<const float4*>(in)[i];
        ushort4 o;
        o.x = f2bf(f.x); o.y = f2bf(f.y); o.z = f2bf(f.z); o.w = f2bf(f.w);
        reinterpret_cast<ushort4*>(out_bf)[i] = o;
        reinterpret_cast<unsigned*>(out8)[i] = pk4fp8(f.x, f.y, f.z, f.w);
    }
}

// ---------- 3 weight casts in one launch ----------
struct WCastArgs { const float* src[3]; u16* dst[3]; };
__global__ __launch_bounds__(256)
void cast_w3(WCastArgs a) {
    const int z = blockIdx.z;
    const int i = blockIdx.x * 256 + threadIdx.x;
    float4 f = reinterpret_cast<const float4*>(a.src[z])[i];
    ushort4 o;
    o.x = f2bf(f.x); o.y = f2bf(f.y); o.z = f2bf(f.z); o.w = f2bf(f.w);
    reinterpret_cast<ushort4*>(a.dst[z])[i] = o;
}

// ---------- bf16 tiled transpose, two tensors per launch ----------
__global__ __launch_bounds__(256)
void transpose_w2(const u16* __restrict__ in0, u16* __restrict__ out0,
                  const u16* __restrict__ in1, u16* __restrict__ out1) {
    __shared__ u16 t[64][72];
    const u16* in = blockIdx.z ? in1 : in0;
    u16* out      = blockIdx.z ? out1 : out0;
    const int R = E_DIM, C = E_DIM;
    const int r0 = blockIdx.y * 64, c0 = blockIdx.x * 64;
    const int tid = threadIdx.x;
    const int lr = tid >> 2, lc = (tid & 3) * 16;
    const u16* src = in + (size_t)(r0 + lr) * C + c0 + lc;
    *reinterpret_cast<uint4*>(&t[lr][lc])     = *reinterpret_cast<const uint4*>(src);
    *reinterpret_cast<uint4*>(&t[lr][lc + 8]) = *reinterpret_cast<const uint4*>(src + 8);
    __syncthreads();
    u16 tmp[16];
#pragma unroll
    for (int j = 0; j < 16; ++j) tmp[j] = t[lc + j][lr];
    u16* dst = out + (size_t)(c0 + lr) * R + r0 + lc;
    *reinterpret_cast<uint4*>(dst)     = *reinterpret_cast<uint4*>(&tmp[0]);
    *reinterpret_cast<uint4*>(dst + 8) = *reinterpret_cast<uint4*>(&tmp[8]);
}

// ---------- bf16 [R x C] -> fp8 transposed [C x R] ----------
__global__ __launch_bounds__(256)
void transpose_to_fp8(const u16* __restrict__ in, u8* __restrict__ out, int R, int C) {
    __shared__ u16 t[64][72];
    const int r0 = blockIdx.y * 64, c0 = blockIdx.x * 64;
    const int tid = threadIdx.x;
    const int lr = tid >> 2, lc = (tid & 3) * 16;
    const u16* src = in + (size_t)(r0 + lr) * C + c0 + lc;
    *reinterpret_cast<uint4*>(&t[lr][lc])     = *reinterpret_cast<const uint4*>(src);
    *reinterpret_cast<uint4*>(&t[lr][lc + 8]) = *reinterpret_cast<const uint4*>(src + 8);
    __syncthreads();
    unsigned w[4];
#pragma unroll
    for (int g = 0; g < 4; ++g)
        w[g] = pk4fp8(bf2f(t[lc + 4 * g + 0][lr]), bf2f(t[lc + 4 * g + 1][lr]),
                      bf2f(t[lc + 4 * g + 2][lr]), bf2f(t[lc + 4 * g + 3][lr]));
    u8* dst = out + (size_t)(c0 + lr) * R + r0 + lc;
    *reinterpret_cast<uint4*>(dst) = (uint4){w[0], w[1], w[2], w[3]};
}

// ---------- 128x256 bf16 MFMA GEMM body (projections / wqkT) ----------
// mode: 1 = bf16 out; 3 = bf16 out + fp8 out (dual)
__device__ __forceinline__
void gemm_wide_body(const u16* __restrict__ A, int lda,
                    const u16* __restrict__ B, int ldb,
                    void* __restrict__ C, int ldc, int K,
                    int row0, int col0, int mode, u8* __restrict__ C2) {
    __shared__ u16 sA[2][128 * 32];
    __shared__ u16 sB[2][256 * 32];

    const int tid  = threadIdx.x;
    const int wave = tid >> 6, lane = tid & 63;
    const int quad = lane >> 4, m16 = lane & 15;
    const int wr = (wave & 1) * 64;
    const int wc = (wave >> 1) * 128;

    const int srow  = lane >> 2;
    const int skoff = (lane & 3) * 8;
    const u16* ag0 = A + (size_t)(row0 + wave * 16 + srow) * lda + skoff;
    const u16* ag1 = ag0 + (size_t)64 * lda;
    const u16* bg0 = B + (size_t)(col0 + wave * 16 + srow) * ldb + skoff;
    const u16* bg1 = bg0 + (size_t)64 * ldb;
    const u16* bg2 = bg0 + (size_t)128 * ldb;
    const u16* bg3 = bg0 + (size_t)192 * ldb;
    const int loa0 = (wave * 16) * 32;
    const int loa1 = (wave * 16 + 64) * 32;
    const int lob0 = (wave * 16) * 32;
    const int lob1 = (wave * 16 + 64) * 32;
    const int lob2 = (wave * 16 + 128) * 32;
    const int lob3 = (wave * 16 + 192) * 32;

    f32x4 acc[4][8];
#pragma unroll
    for (int i = 0; i < 4; ++i)
#pragma unroll
        for (int j = 0; j < 8; ++j) acc[i][j] = (f32x4){0.f, 0.f, 0.f, 0.f};

    GLD16(ag0, &sA[0][loa0]); GLD16(ag1, &sA[0][loa1]);
    GLD16(bg0, &sB[0][lob0]); GLD16(bg1, &sB[0][lob1]);
    GLD16(bg2, &sB[0][lob2]); GLD16(bg3, &sB[0][lob3]);

    int kb = 0;
    for (int k0 = 0; k0 < K; k0 += 32, kb ^= 1) {
        __syncthreads();
        const int kn = (k0 + 32 < K) ? (k0 + 32) : 0;
        GLD16(ag0 + kn, &sA[kb ^ 1][loa0]); GLD16(ag1 + kn, &sA[kb ^ 1][loa1]);
        GLD16(bg0 + kn, &sB[kb ^ 1][lob0]); GLD16(bg1 + kn, &sB[kb ^ 1][lob1]);
        GLD16(bg2 + kn, &sB[kb ^ 1][lob2]); GLD16(bg3 + kn, &sB[kb ^ 1][lob3]);

        bf16x8 a[4], b[8];
#pragma unroll
        for (int i = 0; i < 4; ++i)
            a[i] = *reinterpret_cast<const bf16x8*>(&sA[kb][(wr + i * 16 + m16) * 32 + quad * 8]);
#pragma unroll
        for (int j = 0; j < 8; ++j)
            b[j] = *reinterpret_cast<const bf16x8*>(&sB[kb][(wc + j * 16 + m16) * 32 + quad * 8]);
#pragma unroll
        for (int i = 0; i < 4; ++i)
#pragma unroll
            for (int j = 0; j < 8; ++j)
                acc[i][j] = __builtin_amdgcn_mfma_f32_16x16x32_bf16(a[i], b[j], acc[i][j], 0, 0, 0);
    }

    // epilogue: C/D layout col=lane&15, row=quad*4+r (HW-verified)
#pragma unroll
    for (int i = 0; i < 4; ++i) {
        const int rbase = row0 + wr + i * 16 + quad * 4;
#pragma unroll
        for (int j = 0; j < 8; ++j) {
            const int c = col0 + wc + j * 16 + m16;
#pragma unroll
            for (int r = 0; r < 4; ++r) {
                const float v = acc[i][j][r];
                reinterpret_cast<u16*>(C)[(size_t)(rbase + r) * ldc + c] = f2bf(v);
                if (mode == 3)
                    C2[(size_t)(rbase + r) * ldc + c] = f2fp8(v);
            }
        }
    }
}

// ---------- batched projection GEMMs ----------
struct ProjArgs {
    const u16* A[3];
    const u16* B[3];
    void*      C[3];
    u8*        C2[3];
    int        rows[3];
    int        mode[3];
    int        ldc[3];
};

__global__ __launch_bounds__(256, 2)
void proj_gemm(ProjArgs p) {
    const int z = blockIdx.z;
    const int row0 = blockIdx.y * 128;
    if (row0 >= p.rows[z]) return;
    gemm_wide_body(p.A[z], E_DIM, p.B[z], E_DIM, p.C[z], p.ldc[z], E_DIM,
                   row0, blockIdx.x * 256, p.mode[z], p.C2[z]);
}

__global__ __launch_bounds__(256, 2)
void gemm_main(const u16* __restrict__ A, int lda,
               const u16* __restrict__ B, int ldb,
               void* __restrict__ C, int ldc, int K) {
    gemm_wide_body(A, lda, B, ldb, C, ldc, K,
                   blockIdx.y * 128, blockIdx.x * 256, 1, nullptr);
}

// ---------- score GEMM: all-fp8 inputs, K-step 64, fused exp -> fp8 P~ + psum ----------
// S[i][j] = sum_k T8[i][k] * obs8[j][k]; K = 512, 8 iterations.
__global__ __launch_bounds__(256, 2)
void score_fp8(const u8* __restrict__ A, const u8* __restrict__ B,
               u8* __restrict__ P, float* __restrict__ psum) {
    __shared__ u8 sA[2][128 * 64];   // 8 KB per buffer
    __shared__ u8 sB[2][256 * 64];   // 16 KB per buffer

    const int row0 = blockIdx.y * 128, col0 = blockIdx.x * 256;
    const int tid = threadIdx.x;
    const int wave = tid >> 6, lane = tid & 63;
    const int quad = lane >> 4, m16 = lane & 15;
    const int wr = (wave & 1) * 64, wc = (wave >> 1) * 128;
    const int srow = tid >> 2, soff = (tid & 3) * 16;   // 4 threads per 64B row

    const u8* ag0 = A + (size_t)(row0 + srow) * E_DIM + soff;
    const u8* ag1 = ag0 + (size_t)64 * E_DIM;
    const u8* bg0 = B + (size_t)(col0 + srow) * E_DIM + soff;
    const u8* bg1 = bg0 + (size_t)64 * E_DIM;
    const u8* bg2 = bg0 + (size_t)128 * E_DIM;
    const u8* bg3 = bg0 + (size_t)192 * E_DIM;
    const int dst = tid * 16;

    f32x4 acc[4][8];
#pragma unroll
    for (int i = 0; i < 4; ++i)
#pragma unroll
        for (int j = 0; j < 8; ++j) acc[i][j] = (f32x4){0.f, 0.f, 0.f, 0.f};

    GLD16(ag0, &sA[0][dst]); GLD16(ag1, &sA[0][4096 + dst]);
    GLD16(bg0, &sB[0][dst]); GLD16(bg1, &sB[0][4096 + dst]);
    GLD16(bg2, &sB[0][8192 + dst]); GLD16(bg3, &sB[0][12288 + dst]);

    int kb = 0;
    for (int k0 = 0; k0 < E_DIM; k0 += 64, kb ^= 1) {
        __syncthreads();
        const int kn = (k0 + 64 < E_DIM) ? (k0 + 64) : 0;
        GLD16(ag0 + kn, &sA[kb ^ 1][dst]); GLD16(ag1 + kn, &sA[kb ^ 1][4096 + dst]);
        GLD16(bg0 + kn, &sB[kb ^ 1][dst]); GLD16(bg1 + kn, &sB[kb ^ 1][4096 + dst]);
        GLD16(bg2 + kn, &sB[kb ^ 1][8192 + dst]); GLD16(bg3 + kn, &sB[kb ^ 1][12288 + dst]);

#pragma unroll
        for (int kh = 0; kh < 2; ++kh) {
            long a[4], b[8];
#pragma unroll
            for (int i = 0; i < 4; ++i)
                a[i] = *reinterpret_cast<const long*>(
                    &sA[kb][(wr + i * 16 + m16) * 64 + kh * 32 + quad * 8]);
#pragma unroll
            for (int j = 0; j < 8; ++j)
                b[j] = *reinterpret_cast<const long*>(
                    &sB[kb][(wc + j * 16 + m16) * 64 + kh * 32 + quad * 8]);
#pragma unroll
            for (int i = 0; i < 4; ++i)
#pragma unroll
                for (int j = 0; j < 8; ++j)
                    acc[i][j] = __builtin_amdgcn_mfma_f32_16x16x32_fp8_fp8(a[i], b[j], acc[i][j], 0, 0, 0);
        }
    }

    // epilogue: exp -> fp8 P~ + per-row partial sums (no max subtraction: fp32-safe)
    float* pcol = psum + (size_t)(blockIdx.x * 2 + (wave >> 1)) * N_ROWS;
#pragma unroll
    for (int i = 0; i < 4; ++i) {
        const int rbase = row0 + wr + i * 16 + quad * 4;
        float rs[4] = {0.f, 0.f, 0.f, 0.f};
#pragma unroll
        for (int j = 0; j < 8; ++j) {
            const int c = col0 + wc + j * 16 + m16;
#pragma unroll
            for (int r = 0; r < 4; ++r) {
                const float v = __expf(acc[i][j][r] * INV_T);
                rs[r] += v;
                P[(size_t)(rbase + r) * M_ROWS + c] = f2fp8(v);
            }
        }
#pragma unroll
        for (int r = 0; r < 4; ++r) {
            float s = rs[r];
            s += __shfl_down(s, 8, 16);
            s += __shfl_down(s, 4, 16);
            s += __shfl_down(s, 2, 16);
            s += __shfl_down(s, 1, 16);
            if (m16 == 0) pcol[rbase + r] = s;
        }
    }
}

// ---------- PV GEMM: all-fp8, K-step 64, split-K over grid.z, bf16 out ----------
// O[i][e] = sum_j P[i][j] * VT[e][j]; P [N x M] fp8, VT [E x M] fp8.
__global__ __launch_bounds__(256, 2)
void pv_fp8(const u8* __restrict__ P, const u8* __restrict__ VT,
            u16* __restrict__ O, int Kslice) {
    __shared__ u8 sA[2][128 * 64];
    __shared__ u8 sB[2][256 * 64];

    const int z = blockIdx.z;
    const int row0 = blockIdx.y * 128, col0 = blockIdx.x * 256;
    const int tid = threadIdx.x;
    const int wave = tid >> 6, lane = tid & 63;
    const int quad = lane >> 4, m16 = lane & 15;
    const int wr = (wave & 1) * 64, wc = (wave >> 1) * 128;
    const int srow = tid >> 2, soff = (tid & 3) * 16;

    const u8* ag0 = P  + (size_t)(row0 + srow) * M_ROWS + z * Kslice + soff;
    const u8* ag1 = ag0 + (size_t)64 * M_ROWS;
    const u8* bg0 = VT + (size_t)(col0 + srow) * M_ROWS + z * Kslice + soff;
    const u8* bg1 = bg0 + (size_t)64 * M_ROWS;
    const u8* bg2 = bg0 + (size_t)128 * M_ROWS;
    const u8* bg3 = bg0 + (size_t)192 * M_ROWS;
    const int dst = tid * 16;

    f32x4 acc[4][8];
#pragma unroll
    for (int i = 0; i < 4; ++i)
#pragma unroll
        for (int j = 0; j < 8; ++j) acc[i][j] = (f32x4){0.f, 0.f, 0.f, 0.f};

    GLD16(ag0, &sA[0][dst]); GLD16(ag1, &sA[0][4096 + dst]);
    GLD16(bg0, &sB[0][dst]); GLD16(bg1, &sB[0][4096 + dst]);
    GLD16(bg2, &sB[0][8192 + dst]); GLD16(bg3, &sB[0][12288 + dst]);

    int kb = 0;
    for (int k0 = 0; k0 < Kslice; k0 += 64, kb ^= 1) {
        __syncthreads();
        const int kn = (k0 + 64 < Kslice) ? (k0 + 64) : 0;
        GLD16(ag0 + kn, &sA[kb ^ 1][dst]); GLD16(ag1 + kn, &sA[kb ^ 1][4096 + dst]);
        GLD16(bg0 + kn, &sB[kb ^ 1][dst]); GLD16(bg1 + kn, &sB[kb ^ 1][4096 + dst]);
        GLD16(bg2 + kn, &sB[kb ^ 1][8192 + dst]); GLD16(bg3 + kn, &sB[kb ^ 1][12288 + dst]);

#pragma unroll
        for (int kh = 0; kh < 2; ++kh) {
            long a[4], b[8];
#pragma unroll
            for (int i = 0; i < 4; ++i)
                a[i] = *reinterpret_cast<const long*>(
                    &sA[kb][(wr + i * 16 + m16) * 64 + kh * 32 + quad * 8]);
#pragma unroll
            for (int j = 0; j < 8; ++j)
                b[j] = *reinterpret_cast<const long*>(
                    &sB[kb][(wc + j * 16 + m16) * 64 + kh * 32 + quad * 8]);
#pragma unroll
            for (int i = 0; i < 4; ++i)
#pragma unroll
                for (int j = 0; j < 8; ++j)
                    acc[i][j] = __builtin_amdgcn_mfma_f32_16x16x32_fp8_fp8(a[i], b[j], acc[i][j], 0, 0, 0);
        }
    }

    u16* Oz = O + (size_t)z * N_ROWS * E_DIM;
#pragma unroll
    for (int i = 0; i < 4; ++i) {
        const int rbase = row0 + wr + i * 16 + quad * 4;
#pragma unroll
        for (int j = 0; j < 8; ++j) {
            const int c = col0 + wc + j * 16 + m16;
#pragma unroll
            for (int r = 0; r < 4; ++r)
                Oz[(size_t)(rbase + r) * E_DIM + c] = f2bf(acc[i][j][r]);
        }
    }
}

// ---------- self attention score: dot(T[n], vcode[n]) (bf16) ----------
__global__ __launch_bounds__(256)
void self_dot(const u16* __restrict__ q, const u16* __restrict__ k,
              float* __restrict__ selfS) {
    const int wave = threadIdx.x >> 6, lane = threadIdx.x & 63;
    const int row = blockIdx.x * 4 + wave;
    const uint4 qa = *reinterpret_cast<const uint4*>(q + (size_t)row * E_DIM + lane * 8);
    const uint4 ka = *reinterpret_cast<const uint4*>(k + (size_t)row * E_DIM + lane * 8);
    unsigned qu[4] = {qa.x, qa.y, qa.z, qa.w};
    unsigned ku[4] = {ka.x, ka.y, ka.z, ka.w};
    float s = 0.f;
#pragma unroll
    for (int i = 0; i < 4; ++i) {
        s += bf2f((u16)(qu[i] & 0xFFFF)) * bf2f((u16)(ku[i] & 0xFFFF));
        s += bf2f((u16)(qu[i] >> 16))    * bf2f((u16)(ku[i] >> 16));
    }
#pragma unroll
    for (int off = 32; off; off >>= 1) s += __shfl_down(s, off);
    if (lane == 0) selfS[row] = s;
}

// ---------- combine 32 partial row sums -> inv_l, p0 ----------
__global__ __launch_bounds__(256)
void sum_combine(const float* __restrict__ psum, const float* __restrict__ selfS,
                 float* __restrict__ p0_out, float* __restrict__ invl_out) {
    const int n = blockIdx.x * 256 + threadIdx.x;
    float l = 0.f;
#pragma unroll
    for (int j = 0; j < 32; ++j) l += psum[(size_t)j * N_ROWS + n];
    const float p0 = expf(selfS[n] * INV_T);
    l += p0;
    p0_out[n] = p0;
    invl_out[n] = 1.f / l;
}

// ---------- epilogue: LN(inv_l*(p0*v_value + sum_z O_z) + v_code) ----------
__global__ __launch_bounds__(256)
void final_ln(const u16* __restrict__ O, const u16* __restrict__ vval,
              const float* __restrict__ p0v, const float* __restrict__ invl,
              const float* __restrict__ vcode,
              const float* __restrict__ gamma, const float* __restrict__ beta,
              float* __restrict__ out) {
    __shared__ float lds[8];
    const int n = blockIdx.x, t = threadIdx.x;
    const int lane = t & 63, wave = t >> 6;
    const size_t base = (size_t)n * E_DIM;
    const size_t NE = (size_t)N_ROWS * E_DIM;
    const float a = p0v[n], il = invl[n];

    float o0 = 0.f, o1 = 0.f;
#pragma unroll
    for (int z = 0; z < KSPLIT; ++z) {
        o0 += bf2f(O[z * NE + base + t]);
        o1 += bf2f(O[z * NE + base + t + 256]);
    }
    float x0 = fmaf(a, bf2f(vval[base + t]),       o0) * il + vcode[base + t];
    float x1 = fmaf(a, bf2f(vval[base + t + 256]), o1) * il + vcode[base + t + 256];

    float s = x0 + x1;
#pragma unroll
    for (int off = 32; off; off >>= 1) s += __shfl_down(s, off);
    if (lane == 0) lds[wave] = s;
    __syncthreads();
    const float mu = (lds[0] + lds[1] + lds[2] + lds[3]) * (1.0f / E_DIM);
    __syncthreads();

    const float d0 = x0 - mu, d1 = x1 - mu;
    float vs = d0 * d0 + d1 * d1;
#pragma unroll
    for (int off = 32; off; off >>= 1) vs += __shfl_down(vs, off);
    if (lane == 0) lds[wave] = vs;
    __syncthreads();
    const float var = (lds[0] + lds[1] + lds[2] + lds[3]) * (1.0f / E_DIM);
    const float rs = rsqrtf(var + 1e-6f);

    out[base + t]       = d0 * rs * gamma[t]       + beta[t];
    out[base + t + 256] = d1 * rs * gamma[t + 256] + beta[t + 256];
}

// ---------- workspace layout (bytes; total ~108 MiB) ----------
#define OFF_VCODEBF 0ull
#define OFF_OBSBF   8388608ull
#define OFF_OBS8    12582912ull
#define OFF_WQ      14680064ull
#define OFF_WK      15204352ull
#define OFF_WV      15728640ull
#define OFF_WQT     16252928ull
#define OFF_WKT     16777216ull
#define OFF_WQKT    17301504ull
#define OFF_TBF     17825792ull
#define OFF_T8      26214400ull
#define OFF_OBSV    30408704ull
#define OFF_OBSVT8  34603008ull
#define OFF_VVAL    36700160ull
#define OFF_S8      45088768ull
#define OFF_O       78643200ull
#define OFF_P0      112197632ull
#define OFF_SELF    112230400ull
#define OFF_INVL    112263168ull
#define OFF_PSUM    112295936ull

extern "C" void kernel_launch(void* const* d_in, const int* in_sizes, int n_in,
                              void* d_out, int out_size, void* d_ws, size_t ws_size,
                              hipStream_t stream) {
    const float* v_code   = (const float*)d_in[0];
    const float* obs_code = (const float*)d_in[1];
    const float* Wq       = (const float*)d_in[2];
    const float* Wk       = (const float*)d_in[3];
    const float* Wv       = (const float*)d_in[4];
    const float* gamma    = (const float*)d_in[5];
    const float* beta     = (const float*)d_in[6];
    float* out = (float*)d_out;
    char* ws = (char*)d_ws;

    u16* vcode_bf = (u16*)(ws + OFF_VCODEBF);
    u16* obs_bf   = (u16*)(ws + OFF_OBSBF);
    u8*  obs8     = (u8*)(ws + OFF_OBS8);
    u16* wq_bf    = (u16*)(ws + OFF_WQ);
    u16* wk_bf    = (u16*)(ws + OFF_WK);
    u16* wv_bf    = (u16*)(ws + OFF_WV);
    u16* wqT      = (u16*)(ws + OFF_WQT);
    u16* wkT      = (u16*)(ws + OFF_WKT);
    u16* wqkT     = (u16*)(ws + OFF_WQKT);
    u16* t_bf     = (u16*)(ws + OFF_TBF);
    u8*  t8       = (u8*)(ws + OFF_T8);
    u16* obsv_bf  = (u16*)(ws + OFF_OBSV);
    u8*  obsvT8   = (u8*)(ws + OFF_OBSVT8);
    u16* vval     = (u16*)(ws + OFF_VVAL);
    u8*  S8       = (u8*)(ws + OFF_S8);
    u16* O        = (u16*)(ws + OFF_O);
    float* p0v    = (float*)(ws + OFF_P0);
    float* selfS  = (float*)(ws + OFF_SELF);
    float* invl   = (float*)(ws + OFF_INVL);
    float* psum   = (float*)(ws + OFF_PSUM);

    // 1. casts (vcode bf16; obs bf16+fp8; 3 weights batched)
    cast_bf<<<N_ROWS * E_DIM / 4 / 256, 256, 0, stream>>>(v_code, vcode_bf, N_ROWS * E_DIM / 4);
    cast_obs<<<M_ROWS * E_DIM / 4 / 256, 256, 0, stream>>>(obs_code, obs_bf, obs8, M_ROWS * E_DIM / 4);
    WCastArgs wc;
    wc.src[0] = Wq; wc.dst[0] = wq_bf;
    wc.src[1] = Wk; wc.dst[1] = wk_bf;
    wc.src[2] = Wv; wc.dst[2] = wv_bf;
    cast_w3<<<dim3(E_DIM * E_DIM / 4 / 256, 1, 3), 256, 0, stream>>>(wc);

    // 2. transpose Wq, Wk (one launch)
    transpose_w2<<<dim3(8, 8, 2), 256, 0, stream>>>(wq_bf, wqT, wk_bf, wkT);

    // 3. WqkT = (Wq^T Wk)^T
    gemm_main<<<dim3(E_DIM / 256, E_DIM / 128, 1), 256, 0, stream>>>(
        wkT, E_DIM, wqT, E_DIM, wqkT, E_DIM, E_DIM);

    // 4. projections: vval (bf16), obsv (bf16), T (bf16 + fp8 dual)
    ProjArgs p;
    p.A[0] = vcode_bf; p.B[0] = wv_bf; p.C[0] = vval;    p.C2[0] = nullptr; p.rows[0] = N_ROWS; p.mode[0] = 1; p.ldc[0] = E_DIM;
    p.A[1] = obs_bf;   p.B[1] = wv_bf; p.C[1] = obsv_bf; p.C2[1] = nullptr; p.rows[1] = M_ROWS; p.mode[1] = 1; p.ldc[1] = E_DIM;
    p.A[2] = vcode_bf; p.B[2] = wqkT;  p.C[2] = t_bf;    p.C2[2] = t8;      p.rows[2] = N_ROWS; p.mode[2] = 3; p.ldc[2] = E_DIM;
    proj_gemm<<<dim3(E_DIM / 256, N_ROWS / 128, 3), 256, 0, stream>>>(p);

    // 5. transpose+quantize obsv -> obsvT8 fp8 [512 x 4096]
    transpose_to_fp8<<<dim3(E_DIM / 64, M_ROWS / 64), 256, 0, stream>>>(
        obsv_bf, obsvT8, M_ROWS, E_DIM);

    // 6. self score (bf16 path)
    self_dot<<<N_ROWS / 4, 256, 0, stream>>>(t_bf, vcode_bf, selfS);

    // 7. scores: all-fp8 GEMM, K-step 64, fused exp -> fp8 P~ + psum[32][8192]
    score_fp8<<<dim3(M_ROWS / 256, N_ROWS / 128, 1), 256, 0, stream>>>(
        t8, obs8, S8, psum);

    // 8. combine partials + self term -> p0, 1/l
    sum_combine<<<N_ROWS / 256, 256, 0, stream>>>(psum, selfS, p0v, invl);

    // 9. O_z = P~[:, z-slice] @ V_obs[z-slice, :]  (all-fp8, K-step 64, split-K=4)
    pv_fp8<<<dim3(E_DIM / 256, N_ROWS / 128, KSPLIT), 256, 0, stream>>>(
        S8, obsvT8, O, M_ROWS / KSPLIT);

    // 10. residual + LayerNorm
    final_ln<<<N_ROWS, 256, 0, stream>>>(O, vval, p0v, invl, v_code, gamma, beta, out);
}

// Round 10
// 224.790 us; speedup vs baseline: 1.2229x; 1.2229x over previous
//
#include <hip/hip_runtime.h>
#include <hip/hip_bf16.h>

typedef unsigned short u16;
typedef unsigned char u8;
typedef __bf16 bf16x8 __attribute__((ext_vector_type(8)));
typedef float f32x4 __attribute__((ext_vector_type(4)));

#define N_ROWS 8192
#define M_ROWS 4096
#define E_DIM  512
#define KSPLIT 4
#define INV_T  0.04419417382415922f   // 1/22.627416997969522

// ---------- helpers ----------
__device__ __forceinline__ u16 f2bf(float f) {
    unsigned u = __float_as_uint(f);
    u += 0x7FFF + ((u >> 16) & 1);   // RNE
    return (u16)(u >> 16);
}
__device__ __forceinline__ float bf2f(u16 u) {
    return __uint_as_float(((unsigned)u) << 16);
}
__device__ __forceinline__ u8 f2fp8(float f) {
    int p = __builtin_amdgcn_cvt_pk_fp8_f32(f, f, 0, false);
    return (u8)(p & 0xFF);
}
__device__ __forceinline__ unsigned pk4fp8(float f0, float f1, float f2, float f3) {
    int p01 = __builtin_amdgcn_cvt_pk_fp8_f32(f0, f1, 0, false);
    int p23 = __builtin_amdgcn_cvt_pk_fp8_f32(f2, f3, 0, false);
    return (unsigned)(p01 & 0xFFFF) | ((unsigned)p23 << 16);
}

#define GLD16(gp, lp) \
    __builtin_amdgcn_global_load_lds((const __attribute__((address_space(1))) void*)(gp), \
                                     (__attribute__((address_space(3))) void*)(lp), 16, 0, 0)

// ---------- cast fp32 -> bf16 ----------
__global__ __launch_bounds__(256)
void cast_bf(const float* __restrict__ in, u16* __restrict__ out, int n4) {
    int i = blockIdx.x * 256 + threadIdx.x;
    if (i < n4) {
        float4 f = reinterpret_cast<const float4*>(in)[i];
        ushort4 o;
        o.x = f2bf(f.x); o.y = f2bf(f.y); o.z = f2bf(f.z); o.w = f2bf(f.w);
        reinterpret_cast<ushort4*>(out)[i] = o;
    }
}

// ---------- cast fp32 -> bf16 + fp8 (obs) ----------
__global__ __launch_bounds__(256)
void cast_obs(const float* __restrict__ in, u16* __restrict__ out_bf,
              u8* __restrict__ out8, int n4) {
    int i = blockIdx.x * 256 + threadIdx.x;
    if (i < n4) {
        float4 f = reinterpret_cast<const float4*>(in)[i];
        ushort4 o;
        o.x = f2bf(f.x); o.y = f2bf(f.y); o.z = f2bf(f.z); o.w = f2bf(f.w);
        reinterpret_cast<ushort4*>(out_bf)[i] = o;
        reinterpret_cast<unsigned*>(out8)[i] = pk4fp8(f.x, f.y, f.z, f.w);
    }
}

// ---------- 3 weight casts in one launch ----------
struct WCastArgs { const float* src[3]; u16* dst[3]; };
__global__ __launch_bounds__(256)
void cast_w3(WCastArgs a) {
    const int z = blockIdx.z;
    const int i = blockIdx.x * 256 + threadIdx.x;
    float4 f = reinterpret_cast<const float4*>(a.src[z])[i];
    ushort4 o;
    o.x = f2bf(f.x); o.y = f2bf(f.y); o.z = f2bf(f.z); o.w = f2bf(f.w);
    reinterpret_cast<ushort4*>(a.dst[z])[i] = o;
}

// ---------- bf16 tiled transpose, two tensors per launch ----------
__global__ __launch_bounds__(256)
void transpose_w2(const u16* __restrict__ in0, u16* __restrict__ out0,
                  const u16* __restrict__ in1, u16* __restrict__ out1) {
    __shared__ u16 t[64][72];
    const u16* in = blockIdx.z ? in1 : in0;
    u16* out      = blockIdx.z ? out1 : out0;
    const int R = E_DIM, C = E_DIM;
    const int r0 = blockIdx.y * 64, c0 = blockIdx.x * 64;
    const int tid = threadIdx.x;
    const int lr = tid >> 2, lc = (tid & 3) * 16;
    const u16* src = in + (size_t)(r0 + lr) * C + c0 + lc;
    *reinterpret_cast<uint4*>(&t[lr][lc])     = *reinterpret_cast<const uint4*>(src);
    *reinterpret_cast<uint4*>(&t[lr][lc + 8]) = *reinterpret_cast<const uint4*>(src + 8);
    __syncthreads();
    u16 tmp[16];
#pragma unroll
    for (int j = 0; j < 16; ++j) tmp[j] = t[lc + j][lr];
    u16* dst = out + (size_t)(c0 + lr) * R + r0 + lc;
    *reinterpret_cast<uint4*>(dst)     = *reinterpret_cast<uint4*>(&tmp[0]);
    *reinterpret_cast<uint4*>(dst + 8) = *reinterpret_cast<uint4*>(&tmp[8]);
}

// ---------- bf16 [R x C] -> fp8 transposed [C x R] ----------
__global__ __launch_bounds__(256)
void transpose_to_fp8(const u16* __restrict__ in, u8* __restrict__ out, int R, int C) {
    __shared__ u16 t[64][72];
    const int r0 = blockIdx.y * 64, c0 = blockIdx.x * 64;
    const int tid = threadIdx.x;
    const int lr = tid >> 2, lc = (tid & 3) * 16;
    const u16* src = in + (size_t)(r0 + lr) * C + c0 + lc;
    *reinterpret_cast<uint4*>(&t[lr][lc])     = *reinterpret_cast<const uint4*>(src);
    *reinterpret_cast<uint4*>(&t[lr][lc + 8]) = *reinterpret_cast<const uint4*>(src + 8);
    __syncthreads();
    unsigned w[4];
#pragma unroll
    for (int g = 0; g < 4; ++g)
        w[g] = pk4fp8(bf2f(t[lc + 4 * g + 0][lr]), bf2f(t[lc + 4 * g + 1][lr]),
                      bf2f(t[lc + 4 * g + 2][lr]), bf2f(t[lc + 4 * g + 3][lr]));
    u8* dst = out + (size_t)(c0 + lr) * R + r0 + lc;
    *reinterpret_cast<uint4*>(dst) = (uint4){w[0], w[1], w[2], w[3]};
}

// ---------- 128x256 bf16 MFMA GEMM body (projections / wqkT) ----------
// mode: 1 = bf16 out; 3 = bf16 out + fp8 out (dual)
__device__ __forceinline__
void gemm_wide_body(const u16* __restrict__ A, int lda,
                    const u16* __restrict__ B, int ldb,
                    void* __restrict__ C, int ldc, int K,
                    int row0, int col0, int mode, u8* __restrict__ C2) {
    __shared__ u16 sA[2][128 * 32];
    __shared__ u16 sB[2][256 * 32];

    const int tid  = threadIdx.x;
    const int wave = tid >> 6, lane = tid & 63;
    const int quad = lane >> 4, m16 = lane & 15;
    const int wr = (wave & 1) * 64;
    const int wc = (wave >> 1) * 128;

    const int srow  = lane >> 2;
    const int skoff = (lane & 3) * 8;
    const u16* ag0 = A + (size_t)(row0 + wave * 16 + srow) * lda + skoff;
    const u16* ag1 = ag0 + (size_t)64 * lda;
    const u16* bg0 = B + (size_t)(col0 + wave * 16 + srow) * ldb + skoff;
    const u16* bg1 = bg0 + (size_t)64 * ldb;
    const u16* bg2 = bg0 + (size_t)128 * ldb;
    const u16* bg3 = bg0 + (size_t)192 * ldb;
    const int loa0 = (wave * 16) * 32;
    const int loa1 = (wave * 16 + 64) * 32;
    const int lob0 = (wave * 16) * 32;
    const int lob1 = (wave * 16 + 64) * 32;
    const int lob2 = (wave * 16 + 128) * 32;
    const int lob3 = (wave * 16 + 192) * 32;

    f32x4 acc[4][8];
#pragma unroll
    for (int i = 0; i < 4; ++i)
#pragma unroll
        for (int j = 0; j < 8; ++j) acc[i][j] = (f32x4){0.f, 0.f, 0.f, 0.f};

    GLD16(ag0, &sA[0][loa0]); GLD16(ag1, &sA[0][loa1]);
    GLD16(bg0, &sB[0][lob0]); GLD16(bg1, &sB[0][lob1]);
    GLD16(bg2, &sB[0][lob2]); GLD16(bg3, &sB[0][lob3]);

    int kb = 0;
    for (int k0 = 0; k0 < K; k0 += 32, kb ^= 1) {
        __syncthreads();
        const int kn = (k0 + 32 < K) ? (k0 + 32) : 0;
        GLD16(ag0 + kn, &sA[kb ^ 1][loa0]); GLD16(ag1 + kn, &sA[kb ^ 1][loa1]);
        GLD16(bg0 + kn, &sB[kb ^ 1][lob0]); GLD16(bg1 + kn, &sB[kb ^ 1][lob1]);
        GLD16(bg2 + kn, &sB[kb ^ 1][lob2]); GLD16(bg3 + kn, &sB[kb ^ 1][lob3]);

        bf16x8 a[4], b[8];
#pragma unroll
        for (int i = 0; i < 4; ++i)
            a[i] = *reinterpret_cast<const bf16x8*>(&sA[kb][(wr + i * 16 + m16) * 32 + quad * 8]);
#pragma unroll
        for (int j = 0; j < 8; ++j)
            b[j] = *reinterpret_cast<const bf16x8*>(&sB[kb][(wc + j * 16 + m16) * 32 + quad * 8]);
#pragma unroll
        for (int i = 0; i < 4; ++i)
#pragma unroll
            for (int j = 0; j < 8; ++j)
                acc[i][j] = __builtin_amdgcn_mfma_f32_16x16x32_bf16(a[i], b[j], acc[i][j], 0, 0, 0);
    }

    // epilogue: C/D layout col=lane&15, row=quad*4+r (HW-verified)
#pragma unroll
    for (int i = 0; i < 4; ++i) {
        const int rbase = row0 + wr + i * 16 + quad * 4;
#pragma unroll
        for (int j = 0; j < 8; ++j) {
            const int c = col0 + wc + j * 16 + m16;
#pragma unroll
            for (int r = 0; r < 4; ++r) {
                const float v = acc[i][j][r];
                reinterpret_cast<u16*>(C)[(size_t)(rbase + r) * ldc + c] = f2bf(v);
                if (mode == 3)
                    C2[(size_t)(rbase + r) * ldc + c] = f2fp8(v);
            }
        }
    }
}

// ---------- batched projection GEMMs ----------
struct ProjArgs {
    const u16* A[3];
    const u16* B[3];
    void*      C[3];
    u8*        C2[3];
    int        rows[3];
    int        mode[3];
    int        ldc[3];
};

__global__ __launch_bounds__(256, 2)
void proj_gemm(ProjArgs p) {
    const int z = blockIdx.z;
    const int row0 = blockIdx.y * 128;
    if (row0 >= p.rows[z]) return;
    gemm_wide_body(p.A[z], E_DIM, p.B[z], E_DIM, p.C[z], p.ldc[z], E_DIM,
                   row0, blockIdx.x * 256, p.mode[z], p.C2[z]);
}

__global__ __launch_bounds__(256, 2)
void gemm_main(const u16* __restrict__ A, int lda,
               const u16* __restrict__ B, int ldb,
               void* __restrict__ C, int ldc, int K) {
    gemm_wide_body(A, lda, B, ldb, C, ldc, K,
                   blockIdx.y * 128, blockIdx.x * 256, 1, nullptr);
}

// ---------- score GEMM: all-fp8, K-step 64, XOR-swizzled LDS, fused exp ----------
// Swizzle: LDS slot (row, chunk) holds global chunk (chunk ^ ((row>>1)&3)); 16B chunks.
// Staged by permuting the per-lane global source chunk; dest stays lane*16 (GLD constraint).
// Reader: physical chunk = logical ^ ((m16>>1)&3)  (tile-row offsets all ≡0 mod 4 after >>1).
__global__ __launch_bounds__(256, 2)
void score_fp8(const u8* __restrict__ A, const u8* __restrict__ B,
               u8* __restrict__ P, float* __restrict__ psum) {
    __shared__ u8 sA[2][128 * 64];   // 8 KB per buffer
    __shared__ u8 sB[2][256 * 64];   // 16 KB per buffer

    const int row0 = blockIdx.y * 128, col0 = blockIdx.x * 256;
    const int tid = threadIdx.x;
    const int wave = tid >> 6, lane = tid & 63;
    const int quad = lane >> 4, m16 = lane & 15;
    const int wr = (wave & 1) * 64, wc = (wave >> 1) * 128;
    const int srow = tid >> 2;
    const int soff = (((tid & 3) ^ ((tid >> 3) & 3)) << 4);   // swizzled source chunk
    const int sw4  = (m16 >> 1) & 3;                          // reader swizzle selector

    const u8* ag0 = A + (size_t)(row0 + srow) * E_DIM + soff;
    const u8* ag1 = ag0 + (size_t)64 * E_DIM;
    const u8* bg0 = B + (size_t)(col0 + srow) * E_DIM + soff;
    const u8* bg1 = bg0 + (size_t)64 * E_DIM;
    const u8* bg2 = bg0 + (size_t)128 * E_DIM;
    const u8* bg3 = bg0 + (size_t)192 * E_DIM;
    const int dst = tid * 16;

    f32x4 acc[4][8];
#pragma unroll
    for (int i = 0; i < 4; ++i)
#pragma unroll
        for (int j = 0; j < 8; ++j) acc[i][j] = (f32x4){0.f, 0.f, 0.f, 0.f};

    GLD16(ag0, &sA[0][dst]); GLD16(ag1, &sA[0][4096 + dst]);
    GLD16(bg0, &sB[0][dst]); GLD16(bg1, &sB[0][4096 + dst]);
    GLD16(bg2, &sB[0][8192 + dst]); GLD16(bg3, &sB[0][12288 + dst]);

    int kb = 0;
    for (int k0 = 0; k0 < E_DIM; k0 += 64, kb ^= 1) {
        __syncthreads();
        const int kn = (k0 + 64 < E_DIM) ? (k0 + 64) : 0;
        GLD16(ag0 + kn, &sA[kb ^ 1][dst]); GLD16(ag1 + kn, &sA[kb ^ 1][4096 + dst]);
        GLD16(bg0 + kn, &sB[kb ^ 1][dst]); GLD16(bg1 + kn, &sB[kb ^ 1][4096 + dst]);
        GLD16(bg2 + kn, &sB[kb ^ 1][8192 + dst]); GLD16(bg3 + kn, &sB[kb ^ 1][12288 + dst]);

#pragma unroll
        for (int kh = 0; kh < 2; ++kh) {
            const int off = (((kh * 2 + (quad >> 1)) ^ sw4) << 4) | ((quad & 1) << 3);
            long a[4], b[8];
#pragma unroll
            for (int i = 0; i < 4; ++i)
                a[i] = *reinterpret_cast<const long*>(&sA[kb][(wr + i * 16 + m16) * 64 + off]);
#pragma unroll
            for (int j = 0; j < 8; ++j)
                b[j] = *reinterpret_cast<const long*>(&sB[kb][(wc + j * 16 + m16) * 64 + off]);
#pragma unroll
            for (int i = 0; i < 4; ++i)
#pragma unroll
                for (int j = 0; j < 8; ++j)
                    acc[i][j] = __builtin_amdgcn_mfma_f32_16x16x32_fp8_fp8(a[i], b[j], acc[i][j], 0, 0, 0);
        }
    }

    // epilogue: exp -> fp8 P~ + per-row partial sums (no max subtraction: fp32-safe)
    float* pcol = psum + (size_t)(blockIdx.x * 2 + (wave >> 1)) * N_ROWS;
#pragma unroll
    for (int i = 0; i < 4; ++i) {
        const int rbase = row0 + wr + i * 16 + quad * 4;
        float rs[4] = {0.f, 0.f, 0.f, 0.f};
#pragma unroll
        for (int j = 0; j < 8; ++j) {
            const int c = col0 + wc + j * 16 + m16;
#pragma unroll
            for (int r = 0; r < 4; ++r) {
                const float v = __expf(acc[i][j][r] * INV_T);
                rs[r] += v;
                P[(size_t)(rbase + r) * M_ROWS + c] = f2fp8(v);
            }
        }
#pragma unroll
        for (int r = 0; r < 4; ++r) {
            float s = rs[r];
            s += __shfl_down(s, 8, 16);
            s += __shfl_down(s, 4, 16);
            s += __shfl_down(s, 2, 16);
            s += __shfl_down(s, 1, 16);
            if (m16 == 0) pcol[rbase + r] = s;
        }
    }
}

// ---------- PV GEMM: all-fp8, K-step 64, XOR-swizzled LDS, split-K, bf16 out ----------
__global__ __launch_bounds__(256, 2)
void pv_fp8(const u8* __restrict__ P, const u8* __restrict__ VT,
            u16* __restrict__ O, int Kslice) {
    __shared__ u8 sA[2][128 * 64];
    __shared__ u8 sB[2][256 * 64];

    const int z = blockIdx.z;
    const int row0 = blockIdx.y * 128, col0 = blockIdx.x * 256;
    const int tid = threadIdx.x;
    const int wave = tid >> 6, lane = tid & 63;
    const int quad = lane >> 4, m16 = lane & 15;
    const int wr = (wave & 1) * 64, wc = (wave >> 1) * 128;
    const int srow = tid >> 2;
    const int soff = (((tid & 3) ^ ((tid >> 3) & 3)) << 4);
    const int sw4  = (m16 >> 1) & 3;

    const u8* ag0 = P  + (size_t)(row0 + srow) * M_ROWS + z * Kslice + soff;
    const u8* ag1 = ag0 + (size_t)64 * M_ROWS;
    const u8* bg0 = VT + (size_t)(col0 + srow) * M_ROWS + z * Kslice + soff;
    const u8* bg1 = bg0 + (size_t)64 * M_ROWS;
    const u8* bg2 = bg0 + (size_t)128 * M_ROWS;
    const u8* bg3 = bg0 + (size_t)192 * M_ROWS;
    const int dst = tid * 16;

    f32x4 acc[4][8];
#pragma unroll
    for (int i = 0; i < 4; ++i)
#pragma unroll
        for (int j = 0; j < 8; ++j) acc[i][j] = (f32x4){0.f, 0.f, 0.f, 0.f};

    GLD16(ag0, &sA[0][dst]); GLD16(ag1, &sA[0][4096 + dst]);
    GLD16(bg0, &sB[0][dst]); GLD16(bg1, &sB[0][4096 + dst]);
    GLD16(bg2, &sB[0][8192 + dst]); GLD16(bg3, &sB[0][12288 + dst]);

    int kb = 0;
    for (int k0 = 0; k0 < Kslice; k0 += 64, kb ^= 1) {
        __syncthreads();
        const int kn = (k0 + 64 < Kslice) ? (k0 + 64) : 0;
        GLD16(ag0 + kn, &sA[kb ^ 1][dst]); GLD16(ag1 + kn, &sA[kb ^ 1][4096 + dst]);
        GLD16(bg0 + kn, &sB[kb ^ 1][dst]); GLD16(bg1 + kn, &sB[kb ^ 1][4096 + dst]);
        GLD16(bg2 + kn, &sB[kb ^ 1][8192 + dst]); GLD16(bg3 + kn, &sB[kb ^ 1][12288 + dst]);

#pragma unroll
        for (int kh = 0; kh < 2; ++kh) {
            const int off = (((kh * 2 + (quad >> 1)) ^ sw4) << 4) | ((quad & 1) << 3);
            long a[4], b[8];
#pragma unroll
            for (int i = 0; i < 4; ++i)
                a[i] = *reinterpret_cast<const long*>(&sA[kb][(wr + i * 16 + m16) * 64 + off]);
#pragma unroll
            for (int j = 0; j < 8; ++j)
                b[j] = *reinterpret_cast<const long*>(&sB[kb][(wc + j * 16 + m16) * 64 + off]);
#pragma unroll
            for (int i = 0; i < 4; ++i)
#pragma unroll
                for (int j = 0; j < 8; ++j)
                    acc[i][j] = __builtin_amdgcn_mfma_f32_16x16x32_fp8_fp8(a[i], b[j], acc[i][j], 0, 0, 0);
        }
    }

    u16* Oz = O + (size_t)z * N_ROWS * E_DIM;
#pragma unroll
    for (int i = 0; i < 4; ++i) {
        const int rbase = row0 + wr + i * 16 + quad * 4;
#pragma unroll
        for (int j = 0; j < 8; ++j) {
            const int c = col0 + wc + j * 16 + m16;
#pragma unroll
            for (int r = 0; r < 4; ++r)
                Oz[(size_t)(rbase + r) * E_DIM + c] = f2bf(acc[i][j][r]);
        }
    }
}

// ---------- self attention score: dot(T[n], vcode[n]) (bf16) ----------
__global__ __launch_bounds__(256)
void self_dot(const u16* __restrict__ q, const u16* __restrict__ k,
              float* __restrict__ selfS) {
    const int wave = threadIdx.x >> 6, lane = threadIdx.x & 63;
    const int row = blockIdx.x * 4 + wave;
    const uint4 qa = *reinterpret_cast<const uint4*>(q + (size_t)row * E_DIM + lane * 8);
    const uint4 ka = *reinterpret_cast<const uint4*>(k + (size_t)row * E_DIM + lane * 8);
    unsigned qu[4] = {qa.x, qa.y, qa.z, qa.w};
    unsigned ku[4] = {ka.x, ka.y, ka.z, ka.w};
    float s = 0.f;
#pragma unroll
    for (int i = 0; i < 4; ++i) {
        s += bf2f((u16)(qu[i] & 0xFFFF)) * bf2f((u16)(ku[i] & 0xFFFF));
        s += bf2f((u16)(qu[i] >> 16))    * bf2f((u16)(ku[i] >> 16));
    }
#pragma unroll
    for (int off = 32; off; off >>= 1) s += __shfl_down(s, off);
    if (lane == 0) selfS[row] = s;
}

// ---------- combine 32 partial row sums -> inv_l, p0 ----------
__global__ __launch_bounds__(256)
void sum_combine(const float* __restrict__ psum, const float* __restrict__ selfS,
                 float* __restrict__ p0_out, float* __restrict__ invl_out) {
    const int n = blockIdx.x * 256 + threadIdx.x;
    float l = 0.f;
#pragma unroll
    for (int j = 0; j < 32; ++j) l += psum[(size_t)j * N_ROWS + n];
    const float p0 = expf(selfS[n] * INV_T);
    l += p0;
    p0_out[n] = p0;
    invl_out[n] = 1.f / l;
}

// ---------- epilogue: LN(inv_l*(p0*v_value + sum_z O_z) + v_code) ----------
__global__ __launch_bounds__(256)
void final_ln(const u16* __restrict__ O, const u16* __restrict__ vval,
              const float* __restrict__ p0v, const float* __restrict__ invl,
              const float* __restrict__ vcode,
              const float* __restrict__ gamma, const float* __restrict__ beta,
              float* __restrict__ out) {
    __shared__ float lds[8];
    const int n = blockIdx.x, t = threadIdx.x;
    const int lane = t & 63, wave = t >> 6;
    const size_t base = (size_t)n * E_DIM;
    const size_t NE = (size_t)N_ROWS * E_DIM;
    const float a = p0v[n], il = invl[n];

    float o0 = 0.f, o1 = 0.f;
#pragma unroll
    for (int z = 0; z < KSPLIT; ++z) {
        o0 += bf2f(O[z * NE + base + t]);
        o1 += bf2f(O[z * NE + base + t + 256]);
    }
    float x0 = fmaf(a, bf2f(vval[base + t]),       o0) * il + vcode[base + t];
    float x1 = fmaf(a, bf2f(vval[base + t + 256]), o1) * il + vcode[base + t + 256];

    float s = x0 + x1;
#pragma unroll
    for (int off = 32; off; off >>= 1) s += __shfl_down(s, off);
    if (lane == 0) lds[wave] = s;
    __syncthreads();
    const float mu = (lds[0] + lds[1] + lds[2] + lds[3]) * (1.0f / E_DIM);
    __syncthreads();

    const float d0 = x0 - mu, d1 = x1 - mu;
    float vs = d0 * d0 + d1 * d1;
#pragma unroll
    for (int off = 32; off; off >>= 1) vs += __shfl_down(vs, off);
    if (lane == 0) lds[wave] = vs;
    __syncthreads();
    const float var = (lds[0] + lds[1] + lds[2] + lds[3]) * (1.0f / E_DIM);
    const float rs = rsqrtf(var + 1e-6f);

    out[base + t]       = d0 * rs * gamma[t]       + beta[t];
    out[base + t + 256] = d1 * rs * gamma[t + 256] + beta[t + 256];
}

// ---------- workspace layout (bytes; total ~108 MiB) ----------
#define OFF_VCODEBF 0ull
#define OFF_OBSBF   8388608ull
#define OFF_OBS8    12582912ull
#define OFF_WQ      14680064ull
#define OFF_WK      15204352ull
#define OFF_WV      15728640ull
#define OFF_WQT     16252928ull
#define OFF_WKT     16777216ull
#define OFF_WQKT    17301504ull
#define OFF_TBF     17825792ull
#define OFF_T8      26214400ull
#define OFF_OBSV    30408704ull
#define OFF_OBSVT8  34603008ull
#define OFF_VVAL    36700160ull
#define OFF_S8      45088768ull
#define OFF_O       78643200ull
#define OFF_P0      112197632ull
#define OFF_SELF    112230400ull
#define OFF_INVL    112263168ull
#define OFF_PSUM    112295936ull

extern "C" void kernel_launch(void* const* d_in, const int* in_sizes, int n_in,
                              void* d_out, int out_size, void* d_ws, size_t ws_size,
                              hipStream_t stream) {
    const float* v_code   = (const float*)d_in[0];
    const float* obs_code = (const float*)d_in[1];
    const float* Wq       = (const float*)d_in[2];
    const float* Wk       = (const float*)d_in[3];
    const float* Wv       = (const float*)d_in[4];
    const float* gamma    = (const float*)d_in[5];
    const float* beta     = (const float*)d_in[6];
    float* out = (float*)d_out;
    char* ws = (char*)d_ws;

    u16* vcode_bf = (u16*)(ws + OFF_VCODEBF);
    u16* obs_bf   = (u16*)(ws + OFF_OBSBF);
    u8*  obs8     = (u8*)(ws + OFF_OBS8);
    u16* wq_bf    = (u16*)(ws + OFF_WQ);
    u16* wk_bf    = (u16*)(ws + OFF_WK);
    u16* wv_bf    = (u16*)(ws + OFF_WV);
    u16* wqT      = (u16*)(ws + OFF_WQT);
    u16* wkT      = (u16*)(ws + OFF_WKT);
    u16* wqkT     = (u16*)(ws + OFF_WQKT);
    u16* t_bf     = (u16*)(ws + OFF_TBF);
    u8*  t8       = (u8*)(ws + OFF_T8);
    u16* obsv_bf  = (u16*)(ws + OFF_OBSV);
    u8*  obsvT8   = (u8*)(ws + OFF_OBSVT8);
    u16* vval     = (u16*)(ws + OFF_VVAL);
    u8*  S8       = (u8*)(ws + OFF_S8);
    u16* O        = (u16*)(ws + OFF_O);
    float* p0v    = (float*)(ws + OFF_P0);
    float* selfS  = (float*)(ws + OFF_SELF);
    float* invl   = (float*)(ws + OFF_INVL);
    float* psum   = (float*)(ws + OFF_PSUM);

    // 1. casts (vcode bf16; obs bf16+fp8; 3 weights batched)
    cast_bf<<<N_ROWS * E_DIM / 4 / 256, 256, 0, stream>>>(v_code, vcode_bf, N_ROWS * E_DIM / 4);
    cast_obs<<<M_ROWS * E_DIM / 4 / 256, 256, 0, stream>>>(obs_code, obs_bf, obs8, M_ROWS * E_DIM / 4);
    WCastArgs wc;
    wc.src[0] = Wq; wc.dst[0] = wq_bf;
    wc.src[1] = Wk; wc.dst[1] = wk_bf;
    wc.src[2] = Wv; wc.dst[2] = wv_bf;
    cast_w3<<<dim3(E_DIM * E_DIM / 4 / 256, 1, 3), 256, 0, stream>>>(wc);

    // 2. transpose Wq, Wk (one launch)
    transpose_w2<<<dim3(8, 8, 2), 256, 0, stream>>>(wq_bf, wqT, wk_bf, wkT);

    // 3. WqkT = (Wq^T Wk)^T
    gemm_main<<<dim3(E_DIM / 256, E_DIM / 128, 1), 256, 0, stream>>>(
        wkT, E_DIM, wqT, E_DIM, wqkT, E_DIM, E_DIM);

    // 4. projections: vval (bf16), obsv (bf16), T (bf16 + fp8 dual)
    ProjArgs p;
    p.A[0] = vcode_bf; p.B[0] = wv_bf; p.C[0] = vval;    p.C2[0] = nullptr; p.rows[0] = N_ROWS; p.mode[0] = 1; p.ldc[0] = E_DIM;
    p.A[1] = obs_bf;   p.B[1] = wv_bf; p.C[1] = obsv_bf; p.C2[1] = nullptr; p.rows[1] = M_ROWS; p.mode[1] = 1; p.ldc[1] = E_DIM;
    p.A[2] = vcode_bf; p.B[2] = wqkT;  p.C[2] = t_bf;    p.C2[2] = t8;      p.rows[2] = N_ROWS; p.mode[2] = 3; p.ldc[2] = E_DIM;
    proj_gemm<<<dim3(E_DIM / 256, N_ROWS / 128, 3), 256, 0, stream>>>(p);

    // 5. transpose+quantize obsv -> obsvT8 fp8 [512 x 4096]
    transpose_to_fp8<<<dim3(E_DIM / 64, M_ROWS / 64), 256, 0, stream>>>(
        obsv_bf, obsvT8, M_ROWS, E_DIM);

    // 6. self score (bf16 path)
    self_dot<<<N_ROWS / 4, 256, 0, stream>>>(t_bf, vcode_bf, selfS);

    // 7. scores: all-fp8 GEMM, K-step 64, swizzled LDS, fused exp -> fp8 P~ + psum
    score_fp8<<<dim3(M_ROWS / 256, N_ROWS / 128, 1), 256, 0, stream>>>(
        t8, obs8, S8, psum);

    // 8. combine partials + self term -> p0, 1/l
    sum_combine<<<N_ROWS / 256, 256, 0, stream>>>(psum, selfS, p0v, invl);

    // 9. O_z = P~[:, z-slice] @ V_obs[z-slice, :]  (all-fp8, K-step 64, swizzled, split-K=4)
    pv_fp8<<<dim3(E_DIM / 256, N_ROWS / 128, KSPLIT), 256, 0, stream>>>(
        S8, obsvT8, O, M_ROWS / KSPLIT);

    // 10. residual + LayerNorm
    final_ln<<<N_ROWS, 256, 0, stream>>>(O, vval, p0v, invl, v_code, gamma, beta, out);
}